// Round 9
// baseline (217.657 us; speedup 1.0000x reference)
//
#include <hip/hip_runtime.h>
#include <math.h>

#define NQ    6
#define QDIM  64
#define BB    128
#define CC    64
#define TT    2048
#define DD    256
#define NCH   128
#define CHLEN 16
#define HH    128
#define NCP   60

typedef __bf16 bf16x8 __attribute__((ext_vector_type(8)));
typedef float  f32x4  __attribute__((ext_vector_type(4)));

__device__ __forceinline__ float fast_tanh(float x) {
  float e = __expf(2.f * x);
  return 1.f - 2.f / (e + 1.f);
}

__device__ __forceinline__ float wave_sum(float v) {
#pragma unroll
  for (int off = 32; off >= 1; off >>= 1) v += __shfl_xor(v, off, 64);
  return v;
}

// ---- quantum gates: one statevector per wave, (re,im) per lane ----
__device__ __forceinline__ void g_rx(float& re, float& im, int lane, int m, float half) {
  float c = __cosf(half), s = __sinf(half);
  float pre = __shfl_xor(re, m, 64);
  float pim = __shfl_xor(im, m, 64);
  float nre = c * re + s * pim;
  float nim = c * im - s * pre;
  re = nre; im = nim;
}
__device__ __forceinline__ void g_ry(float& re, float& im, int lane, int m, float half) {
  float c = __cosf(half), s = __sinf(half);
  float pre = __shfl_xor(re, m, 64);
  float pim = __shfl_xor(im, m, 64);
  float sg = (lane & m) ? s : -s;
  re = c * re + sg * pre;
  im = c * im + sg * pim;
}
__device__ __forceinline__ void g_rz(float& re, float& im, int lane, int m, float half) {
  float c = __cosf(half), s = __sinf(half);
  float sg = (lane & m) ? s : -s;
  float nre = c * re - sg * im;
  float nim = c * im + sg * re;
  re = nre; im = nim;
}
__device__ __forceinline__ void g_crx(float& re, float& im, int lane, int mc, int mt, float half) {
  float c = __cosf(half), s = __sinf(half);
  float pre = __shfl_xor(re, mt, 64);
  float pim = __shfl_xor(im, mt, 64);
  if (lane & mc) {
    float nre = c * re + s * pim;
    float nim = c * im - s * pre;
    re = nre; im = nim;
  }
}
__device__ __forceinline__ void ansatz_layer(float& re, float& im, int lane,
                                             const float* p) {
#pragma unroll
  for (int q = 0; q < 6; ++q) {
    int m = 1 << (5 - q);
    g_rx(re, im, lane, m, 0.5f * p[3 * q + 0]);
    g_ry(re, im, lane, m, 0.5f * p[3 * q + 1]);
    g_rz(re, im, lane, m, 0.5f * p[3 * q + 2]);
  }
#pragma unroll
  for (int q = 0; q < 6; ++q)
    g_crx(re, im, lane, 1 << (5 - q), 1 << (5 - ((q + 1) % 6)), 0.5f * p[18 + q]);
#pragma unroll
  for (int q = 5; q >= 0; --q)
    g_crx(re, im, lane, 1 << (5 - q), 1 << (5 - ((q + 5) % 6)), 0.5f * p[24 + (5 - q)]);
}

// ============ K0: fused-weight prep + mixedRaw zeroing ============
// W_fusedT[j][k] = sum_d emb_w[k,d]*att_w1[d,j]         (128 x 64)
// P_fusedT[n][k] = sum_d emb_w[k,d]*proj_w[d,n] (n<60)  (64 x 64, rows>=60 = 0)
// b_fused[j]  = sum_d emb_b[d]*att_w1[d,j] + att_b1[j]
// pb_fused[n] = sum_d emb_b[d]*proj_w[d,n] + proj_b[n]
__global__ __launch_bounds__(256) void k0_prep(
    const float* __restrict__ emb_w, const float* __restrict__ emb_b,
    const float* __restrict__ att_w1, const float* __restrict__ att_b1,
    const float* __restrict__ proj_w, const float* __restrict__ proj_b,
    __bf16* __restrict__ WfH, __bf16* __restrict__ WfL,
    __bf16* __restrict__ PfH, __bf16* __restrict__ PfL,
    float* __restrict__ b_fused, float* __restrict__ pb_fused,
    float* __restrict__ mixedRaw) {
  int idx = blockIdx.x * 256 + threadIdx.x;
  if (idx < 8192) {                         // W_fusedT
    int j = idx & 127, k = idx >> 7;
    float a = 0.f;
    for (int d = 0; d < 256; ++d)
      a = fmaf(emb_w[k * 256 + d], att_w1[d * 128 + j], a);
    __bf16 h = (__bf16)a;
    WfH[j * 64 + k] = h; WfL[j * 64 + k] = (__bf16)(a - (float)h);
  } else if (idx < 12288) {                 // P_fusedT
    int i = idx - 8192;
    int n = i & 63, k = i >> 6;
    float a = 0.f;
    if (n < 60)
      for (int d = 0; d < 256; ++d)
        a = fmaf(emb_w[k * 256 + d], proj_w[d * 60 + n], a);
    __bf16 h = (__bf16)a;
    PfH[n * 64 + k] = h; PfL[n * 64 + k] = (__bf16)(a - (float)h);
  } else if (idx < 12416) {                 // b_fused
    int j = idx - 12288;
    float a = att_b1[j];
    for (int d = 0; d < 256; ++d) a = fmaf(emb_b[d], att_w1[d * 128 + j], a);
    b_fused[j] = a;
  } else if (idx < 12480) {                 // pb_fused
    int n = idx - 12416;
    float a = 0.f;
    if (n < 60) {
      a = proj_b[n];
      for (int d = 0; d < 256; ++d) a = fmaf(emb_b[d], proj_w[d * 60 + n], a);
    }
    pb_fused[n] = a;
  } else if (idx >= 16384) {                // zero LCU accumulator (16384 floats)
    mixedRaw[idx - 16384] = 0.f;
  }
}

// ============ K1: 4 chunks/block, fused GEMM+softmax+xagg+params+ansatz+mix ==
// Split-bf16 3-product MFMA. m89 layouts: A[m=lane&15][k=quad*8+j],
// B[n=lane&15][k=quad*8+j], C: n=lane&15, m=quad*4+reg.
// h = tanh(x^T @ W_fused + b_fused), K=64; params via bilinear chunk identity.
// All 4 waves evolve one chunk each, then atomically accumulate the LCU mix
// (linear => order-free up to fp32 rounding) into mixedRaw[b][lane].
// LDS ~20.7 KB; (256,4) caps VGPR at 128 (R5-proven, no spill).
__global__ __launch_bounds__(256, 4) void k1_fused(
    const float* __restrict__ x, const float* __restrict__ att_w2,
    const __bf16* __restrict__ WfH, const __bf16* __restrict__ WfL,
    const __bf16* __restrict__ PfH, const __bf16* __restrict__ PfL,
    const float* __restrict__ b_fused, const float* __restrict__ pb_fused,
    const float* __restrict__ mix_re, const float* __restrict__ mix_im,
    float* __restrict__ mixedRaw) {
  const int blk = blockIdx.x;            // 4096 = 128 b x 32 chunk-quads
  const int b = blk >> 5, cq = blk & 31;
  const int tid = threadIdx.x, wv = tid >> 6, lane = tid & 63;
  const int l15 = lane & 15, quad = lane >> 4;

  __shared__ float xtile[64][68];        // x^T [t][k] fp32 (word-stride 68)
  __shared__ float scoreS[4][64];
  __shared__ float wSm[4][16];
  __shared__ float xaggS[4][64];
  __shared__ float paramsS[4][60];

  {  // stage x[b, k, cq*64+t] -> xtile[t][k]; 4 passes, coalesced 16B loads
#pragma unroll
    for (int pass = 0; pass < 4; ++pass) {
      int k = pass * 16 + (tid >> 4), t4 = tid & 15;
      float4 v = *(const float4*)(x + ((size_t)(b * 64 + k)) * 2048 + cq * 64 + t4 * 4);
      xtile[t4 * 4 + 0][k] = v.x; xtile[t4 * 4 + 1][k] = v.y;
      xtile[t4 * 4 + 2][k] = v.z; xtile[t4 * 4 + 3][k] = v.w;
    }
  }
  // epilogue constants (4 VGPRs, no barrier crossing issue)
  float w2v[2], b1v[2];
#pragma unroll
  for (int jt = 0; jt < 2; ++jt) {
    int j = wv * 32 + jt * 16 + l15;
    w2v[jt] = att_w2[j];
    b1v[jt] = b_fused[j];
  }
  __syncthreads();

  // ---- GEMM_h: h_pre[64][128] = x^T @ W_fused; wave owns j = wv*32..+31 ----
  f32x4 acc[4][2];                       // [mt][jt]
#pragma unroll
  for (int mt = 0; mt < 4; ++mt)
#pragma unroll
    for (int jt = 0; jt < 2; ++jt) acc[mt][jt] = (f32x4){0.f, 0.f, 0.f, 0.f};
  {
    bf16x8 bh[2][2], bl[2][2];           // [jt][ks], loop-invariant over mt
#pragma unroll
    for (int jt = 0; jt < 2; ++jt)
#pragma unroll
      for (int ks = 0; ks < 2; ++ks) {
        const size_t row = (size_t)(wv * 32 + jt * 16 + l15) * 64 + ks * 32 + 8 * quad;
        bh[jt][ks] = *(const bf16x8*)(WfH + row);
        bl[jt][ks] = *(const bf16x8*)(WfL + row);
      }
#pragma unroll
    for (int mt = 0; mt < 4; ++mt) {     // mt-sectioned A to bound liveness
      bf16x8 ah[2], al[2];
#pragma unroll
      for (int ks = 0; ks < 2; ++ks) {
        const float* src = &xtile[mt * 16 + l15][ks * 32 + 8 * quad];
        float4 u0 = *(const float4*)src, u1 = *(const float4*)(src + 4);
        float vals[8] = {u0.x, u0.y, u0.z, u0.w, u1.x, u1.y, u1.z, u1.w};
#pragma unroll
        for (int j = 0; j < 8; ++j) {
          __bf16 h = (__bf16)vals[j];
          ah[ks][j] = h;
          al[ks][j] = (__bf16)(vals[j] - (float)h);
        }
      }
#pragma unroll
      for (int jt = 0; jt < 2; ++jt)
#pragma unroll
        for (int ks = 0; ks < 2; ++ks) {
          acc[mt][jt] = __builtin_amdgcn_mfma_f32_16x16x32_bf16(ah[ks], bh[jt][ks], acc[mt][jt], 0, 0, 0);
          acc[mt][jt] = __builtin_amdgcn_mfma_f32_16x16x32_bf16(al[ks], bh[jt][ks], acc[mt][jt], 0, 0, 0);
          acc[mt][jt] = __builtin_amdgcn_mfma_f32_16x16x32_bf16(ah[ks], bl[jt][ks], acc[mt][jt], 0, 0, 0);
        }
    }
  }
  {  // scores: tanh, * w2, reduce over the 16 j's in l15; chunk c == mt
#pragma unroll
    for (int mt = 0; mt < 4; ++mt)
#pragma unroll
      for (int r = 0; r < 4; ++r) {
        float sc = fast_tanh(acc[mt][0][r] + b1v[0]) * w2v[0] +
                   fast_tanh(acc[mt][1][r] + b1v[1]) * w2v[1];
        sc += __shfl_xor(sc, 1, 64);
        sc += __shfl_xor(sc, 2, 64);
        sc += __shfl_xor(sc, 4, 64);
        sc += __shfl_xor(sc, 8, 64);
        if (l15 == 0) scoreS[wv][mt * 16 + quad * 4 + r] = sc;
      }
  }
  __syncthreads();

  if (tid < 4) {  // softmax over 16 per chunk (att_b2 dropped: shift-invariant)
    float s[16], mx = -1e30f;
#pragma unroll
    for (int t = 0; t < 16; ++t) {
      int tt = tid * 16 + t;
      s[t] = (scoreS[0][tt] + scoreS[1][tt]) + (scoreS[2][tt] + scoreS[3][tt]);
      mx = fmaxf(mx, s[t]);
    }
    float sum = 0.f;
#pragma unroll
    for (int t = 0; t < 16; ++t) { s[t] = __expf(s[t] - mx); sum += s[t]; }
    float inv = 1.f / sum;
#pragma unroll
    for (int t = 0; t < 16; ++t) wSm[tid][t] = s[t] * inv;
  }
  __syncthreads();

  {  // xagg[c][k] = sum_t w[c,t]*x[c*16+t][k] (fp32, exact); 256 threads
    const int c = tid >> 6, k = tid & 63;
    float a = 0.f;
#pragma unroll
    for (int t = 0; t < 16; ++t) a = fmaf(wSm[c][t], xtile[c * 16 + t][k], a);
    xaggS[c][k] = a;
  }
  __syncthreads();

  {  // params[4][60] = sigmoid(xagg @ P_fused + pb_fused)
    const int jout = wv * 16 + l15;
    f32x4 acc3 = (f32x4){0.f, 0.f, 0.f, 0.f};
#pragma unroll
    for (int ks = 0; ks < 2; ++ks) {
      const size_t row = (size_t)jout * 64 + ks * 32 + 8 * quad;
      bf16x8 bh = *(const bf16x8*)(PfH + row);
      bf16x8 bl = *(const bf16x8*)(PfL + row);
      bf16x8 ax = (bf16x8)(__bf16)0.f, alx = (bf16x8)(__bf16)0.f;
      if (l15 < 4) {
        const float* cs = &xaggS[l15][ks * 32 + 8 * quad];
        float4 u0 = *(const float4*)cs, u1 = *(const float4*)(cs + 4);
        float vals[8] = {u0.x, u0.y, u0.z, u0.w, u1.x, u1.y, u1.z, u1.w};
#pragma unroll
        for (int j = 0; j < 8; ++j) {
          __bf16 h = (__bf16)vals[j];
          ax[j] = h;
          alx[j] = (__bf16)(vals[j] - (float)h);
        }
      }
      acc3 = __builtin_amdgcn_mfma_f32_16x16x32_bf16(ax, bh, acc3, 0, 0, 0);
      acc3 = __builtin_amdgcn_mfma_f32_16x16x32_bf16(alx, bh, acc3, 0, 0, 0);
      acc3 = __builtin_amdgcn_mfma_f32_16x16x32_bf16(ax, bl, acc3, 0, 0, 0);
    }
    if (jout < 60 && quad == 0) {
      float pbias = pb_fused[jout];
#pragma unroll
      for (int r = 0; r < 4; ++r) {      // m = r = chunk c
        float a = acc3[r] + pbias;
        paramsS[r][jout] = 1.f / (1.f + __expf(-a));
      }
    }
  }
  __syncthreads();

  {  // fused ansatz (each wave its chunk) + atomic LCU accumulate
    float re = (lane == 0) ? 1.f : 0.f, im = 0.f;
    const float* p = paramsS[wv];
    ansatz_layer(re, im, lane, p);
    ansatz_layer(re, im, lane, p + 30);
    const int t = cq * 4 + wv;
    float cr = mix_re[t], ci = mix_im[t];
    float wr = cr * re - ci * im;
    float wi = cr * im + ci * re;
    float* mp = mixedRaw + (((size_t)b * 64 + lane) << 1);
    atomicAdd(mp + 0, wr);
    atomicAdd(mp + 1, wi);
  }
}

// ============ K3: normalize + qff ansatz + expvals + head (512 thr) ============
__global__ __launch_bounds__(512) void k3_head(
    const float* __restrict__ mixedRaw, const float* __restrict__ mix_re,
    const float* __restrict__ mix_im, const float* __restrict__ qff,
    const float* __restrict__ out_w, const float* __restrict__ out_b,
    const float* __restrict__ ln_g, const float* __restrict__ ln_b,
    const float* __restrict__ cls_w1, const float* __restrict__ cls_b1,
    const float* __restrict__ cls_w2, const float* __restrict__ cls_b2,
    float* __restrict__ outp) {
  const int b = blockIdx.x, tid = threadIdx.x, wv = tid >> 6, lane = tid & 63;
  __shared__ float stateS[2][64];
  __shared__ float qfeatS[18];
  __shared__ float outS[DD];
  __shared__ float redS[8];
  __shared__ float clsR[2][DD];

  if (wv == 0) {
    // mixed_final = raw/(||raw|| + S*1e-9): exact algebra of ref's
    // coeffs/S, mixed/S, then /(||mixed||+1e-9)
    float2 m = ((const float2*)mixedRaw)[b * 64 + lane];
    float r0 = mix_re[lane], i0 = mix_im[lane];
    float r1 = mix_re[lane + 64], i1 = mix_im[lane + 64];
    float sp = sqrtf(r0 * r0 + i0 * i0) + sqrtf(r1 * r1 + i1 * i1);
    float S = wave_sum(sp) + 1e-8f;
    float re = m.x, im = m.y;
    float n2 = wave_sum(re * re + im * im);
    float scl = 1.f / (sqrtf(n2) + S * 1e-9f);
    re *= scl; im *= scl;
    float qp[30];
#pragma unroll
    for (int i = 0; i < 30; ++i) qp[i] = qff[i];
    ansatz_layer(re, im, lane, qp);
    stateS[0][lane] = re; stateS[1][lane] = im;
  }
  __syncthreads();

  if (wv < 6) {  // expvals parallel: wave wv handles qubit wv (X,Y,Z)
    const int m = 1 << (5 - wv);
    float re = stateS[0][lane], im = stateS[1][lane];
    float pre = stateS[0][lane ^ m], pim = stateS[1][lane ^ m];
    float vx = re * pre + im * pim;
    float vy = (lane & m) ? (im * pre - re * pim) : (re * pim - im * pre);
    float vz = (lane & m) ? -(re * re + im * im) : (re * re + im * im);
    vx = wave_sum(vx); vy = wave_sum(vy); vz = wave_sum(vz);
    if (lane == 0) { qfeatS[wv] = vx; qfeatS[6 + wv] = vy; qfeatS[12 + wv] = vz; }
  }
  __syncthreads();

  float o = 0.f, dv = 0.f;
  if (tid < 256) {
    o = out_b[tid];
#pragma unroll
    for (int k = 0; k < 18; ++k) o = fmaf(qfeatS[k], out_w[k * DD + tid], o);
    float s1 = wave_sum(o);
    if (lane == 0) redS[wv] = s1;
  }
  __syncthreads();
  float mu = (redS[0] + redS[1] + redS[2] + redS[3]) * (1.f / 256.f);
  if (tid < 256) {
    dv = o - mu;
    float s2 = wave_sum(dv * dv);
    if (lane == 0) redS[wv] = s2;
  }
  __syncthreads();
  float var = (redS[0] + redS[1] + redS[2] + redS[3]) * (1.f / 256.f);
  if (tid < 256) {
    outS[tid] = dv / sqrtf(var + 1e-5f) * ln_g[tid] + ln_b[tid];
  }
  __syncthreads();

  {
    const int dd = tid & 255, hh = tid >> 8;
    float r = (hh == 0) ? cls_b1[dd] : 0.f;
#pragma unroll 8
    for (int d = hh * 128; d < hh * 128 + 128; ++d)
      r = fmaf(outS[d], cls_w1[(size_t)d * DD + dd], r);
    clsR[hh][dd] = r;
  }
  __syncthreads();
  if (tid < 256) {
    float r = fmaxf(clsR[0][tid] + clsR[1][tid], 0.f);
    float p0 = wave_sum(r * cls_w2[tid * 2 + 0]);
    float p1 = wave_sum(r * cls_w2[tid * 2 + 1]);
    if (lane == 0) { stateS[0][wv] = p0; stateS[1][wv] = p1; }
  }
  __syncthreads();
  if (tid == 0) {
    outp[b * 2 + 0] = (stateS[0][0] + stateS[0][1]) + (stateS[0][2] + stateS[0][3]) + cls_b2[0];
    outp[b * 2 + 1] = (stateS[1][0] + stateS[1][1]) + (stateS[1][2] + stateS[1][3]) + cls_b2[1];
  }
}

extern "C" void kernel_launch(void* const* d_in, const int* in_sizes, int n_in,
                              void* d_out, int out_size, void* d_ws, size_t ws_size,
                              hipStream_t stream) {
  const float* x      = (const float*)d_in[0];
  const float* emb_w  = (const float*)d_in[1];
  const float* emb_b  = (const float*)d_in[2];
  const float* att_w1 = (const float*)d_in[3];
  const float* att_b1 = (const float*)d_in[4];
  const float* att_w2 = (const float*)d_in[5];
  // d_in[6] att_b2: unused (softmax shift-invariant)
  const float* proj_w = (const float*)d_in[7];
  const float* proj_b = (const float*)d_in[8];
  const float* mix_re = (const float*)d_in[9];
  const float* mix_im = (const float*)d_in[10];
  const float* qff    = (const float*)d_in[11];
  const float* out_w  = (const float*)d_in[12];
  const float* out_b  = (const float*)d_in[13];
  const float* ln_g   = (const float*)d_in[14];
  const float* ln_b   = (const float*)d_in[15];
  const float* cls_w1 = (const float*)d_in[16];
  const float* cls_b1 = (const float*)d_in[17];
  const float* cls_w2 = (const float*)d_in[18];
  const float* cls_b2 = (const float*)d_in[19];

  char* ws = (char*)d_ws;
  float* mixedRaw = (float*)ws;                      // 128*64*2*4 = 65,536
  size_t off = 65536;
  __bf16* WfH = (__bf16*)(ws + off); off += 16384;   // 128x64 bf16
  __bf16* WfL = (__bf16*)(ws + off); off += 16384;
  __bf16* PfH = (__bf16*)(ws + off); off += 8192;    // 64x64 bf16
  __bf16* PfL = (__bf16*)(ws + off); off += 8192;
  float* b_fused  = (float*)(ws + off); off += 512;
  float* pb_fused = (float*)(ws + off); off += 256;

  k0_prep<<<128, 256, 0, stream>>>(emb_w, emb_b, att_w1, att_b1, proj_w, proj_b,
                                   WfH, WfL, PfH, PfL, b_fused, pb_fused,
                                   mixedRaw);
  k1_fused<<<BB * 32, 256, 0, stream>>>(
      x, att_w2, WfH, WfL, PfH, PfL, b_fused, pb_fused, mix_re, mix_im,
      mixedRaw);
  k3_head<<<BB, 512, 0, stream>>>(mixedRaw, mix_re, mix_im, qff, out_w, out_b,
                                  ln_g, ln_b, cls_w1, cls_b1, cls_w2, cls_b2,
                                  (float*)d_out);
}